// Round 1
// baseline (268.228 us; speedup 1.0000x reference)
//
#include <hip/hip_runtime.h>
#include <hip/hip_bf16.h>

// MHA forward: b=2, s=2048, d=1024, h=16, dk=64. fp32 in/out, bf16 MFMA internally.
// ws layout (40.5 MB total):
//   0      : xb  [4096][1024] bf16 (8MB)  -- reused as Ob after GEMM1
//   8 MB   : Wqkvb [3072][1024] bf16 (6MB)   rows 0-1023=Wq/8, 1024-2047=Wk, 2048-3071=Wv
//   14 MB  : Wob [1024][1024] bf16 (2MB)
//   16 MB  : Qb  [4096][1024] bf16 (8MB)  (RoPE'd, pre-scaled by 1/8 via Wq)
//   24 MB  : Kb  [4096][1024] bf16 (8MB)  (RoPE'd)
//   32 MB  : Vb  [4096][1024] bf16 (8MB)
//   40 MB  : cosT [2048][32] f32, sinT [2048][32] f32 (512KB)

typedef __attribute__((ext_vector_type(8))) __bf16 bf16x8;
typedef __attribute__((ext_vector_type(4))) float f32x4;
typedef __attribute__((ext_vector_type(4))) int int4v;
typedef __attribute__((ext_vector_type(2))) unsigned int uint2v;

#define MFMA16(a, b, c) __builtin_amdgcn_mfma_f32_16x16x32_bf16(a, b, c, 0, 0, 0)

union U8 { short s[8]; bf16x8 v; };

__device__ inline unsigned short f2b(float f) {
  unsigned u = __builtin_bit_cast(unsigned, f);
  u = (u + 0x7FFF + ((u >> 16) & 1)) >> 16;   // RNE, finite inputs only
  return (unsigned short)u;
}

// ---------------- prep kernels ----------------

__global__ void convert_f32_bf16(const float* __restrict__ src,
                                 unsigned short* __restrict__ dst,
                                 int n, float scale) {
  int i = (blockIdx.x * blockDim.x + threadIdx.x) * 4;
  if (i + 3 < n) {
    float4 v = *(const float4*)(src + i);
    unsigned p0 = (unsigned)f2b(v.x * scale) | ((unsigned)f2b(v.y * scale) << 16);
    unsigned p1 = (unsigned)f2b(v.z * scale) | ((unsigned)f2b(v.w * scale) << 16);
    uint2v p = {p0, p1};
    *(uint2v*)(dst + i) = p;
  }
}

__global__ void rope_tables(const int* __restrict__ tp,
                            float* __restrict__ cosT, float* __restrict__ sinT) {
  int idx = blockIdx.x * blockDim.x + threadIdx.x;   // 2048*32
  int p = idx >> 5, i = idx & 31;
  float pos = (float)tp[p];
  float freq = powf(10000.0f, -(float)i / 32.0f);
  float ang = pos * freq;
  cosT[idx] = cosf(ang);
  sinT[idx] = sinf(ang);
}

// ---------------- GEMM 1: QKV projection + RoPE epilogue ----------------
// C[4096][3072] = xb[4096][1024] @ Wqkvb^T ; 128x128 tile, BK=32, 4 waves (2x2 of 64x64)

__global__ __launch_bounds__(256) void gemm_qkv_kernel(
    const unsigned short* __restrict__ A,    // xb
    const unsigned short* __restrict__ B,    // Wqkvb (B^T layout: row n = weight row n)
    unsigned short* __restrict__ Qb, unsigned short* __restrict__ Kb,
    unsigned short* __restrict__ Vb,
    const float* __restrict__ cosT, const float* __restrict__ sinT) {
  __shared__ unsigned short As[128 * 32];
  __shared__ unsigned short Bs[128 * 32];
  const int m0 = blockIdx.y * 128, n0 = blockIdx.x * 128;
  const int tid = threadIdx.x, w = tid >> 6, lane = tid & 63;
  const int l15 = lane & 15, l4 = lane >> 4;
  const int wr = w >> 1, wc = w & 1;
  const int srow = lane >> 2, scol = (lane & 3) * 8;

  f32x4 acc[4][4] = {};

  for (int k0 = 0; k0 < 1024; k0 += 32) {
    __syncthreads();
#pragma unroll
    for (int c = 0; c < 2; ++c) {
      const int rb = (w * 2 + c) * 16;   // 16 rows per 1KB wave-call
      const unsigned short* ga = A + (size_t)(m0 + rb + srow) * 1024 + k0 + scol;
      __builtin_amdgcn_global_load_lds(
          (const __attribute__((address_space(1))) void*)ga,
          (__attribute__((address_space(3))) void*)(&As[rb * 32]), 16, 0, 0);
      const unsigned short* gb = B + (size_t)(n0 + rb + srow) * 1024 + k0 + scol;
      __builtin_amdgcn_global_load_lds(
          (const __attribute__((address_space(1))) void*)gb,
          (__attribute__((address_space(3))) void*)(&Bs[rb * 32]), 16, 0, 0);
    }
    __syncthreads();
    bf16x8 af[4], bfr[4];
#pragma unroll
    for (int m = 0; m < 4; m++)
      af[m] = *(const bf16x8*)(&As[(wr * 64 + m * 16 + l15) * 32 + l4 * 8]);
#pragma unroll
    for (int n = 0; n < 4; n++)
      bfr[n] = *(const bf16x8*)(&Bs[(wc * 64 + n * 16 + l15) * 32 + l4 * 8]);
#pragma unroll
    for (int m = 0; m < 4; m++)
#pragma unroll
      for (int n = 0; n < 4; n++)
        acc[m][n] = MFMA16(af[m], bfr[n], acc[m][n]);
  }

  const bool rope = (n0 < 2048);
  unsigned short* dst = (n0 < 1024) ? Qb : (n0 < 2048 ? Kb : Vb);
  const int cbase = (n0 & 1023);
#pragma unroll
  for (int m = 0; m < 4; m++) {
#pragma unroll
    for (int n = 0; n < 4; n++) {
#pragma unroll
      for (int r = 0; r < 4; r++) {
        int row = m0 + wr * 64 + m * 16 + l4 * 4 + r;        // global token row
        int col = cbase + wc * 64 + n * 16 + l15;            // 0..1023
        float v = acc[m][n][r];
        if (rope) {
          float partner = __shfl_xor(v, 1, 64);              // col^1 lives in lane^1
          int pos = row & 2047;
          int pi = (col & 63) >> 1;
          float c = cosT[pos * 32 + pi], s = sinT[pos * 32 + pi];
          v = (col & 1) ? fmaf(v, c, partner * s) : fmaf(v, c, -partner * s);
        }
        dst[(size_t)row * 1024 + col] = f2b(v);
      }
    }
  }
}

// ---------------- GEMM 2: output projection ----------------

__global__ __launch_bounds__(256) void gemm_out_kernel(
    const unsigned short* __restrict__ A,    // Ob [4096][1024]
    const unsigned short* __restrict__ B,    // Wob [1024][1024]
    float* __restrict__ out) {
  __shared__ unsigned short As[128 * 32];
  __shared__ unsigned short Bs[128 * 32];
  const int m0 = blockIdx.y * 128, n0 = blockIdx.x * 128;
  const int tid = threadIdx.x, w = tid >> 6, lane = tid & 63;
  const int l15 = lane & 15, l4 = lane >> 4;
  const int wr = w >> 1, wc = w & 1;
  const int srow = lane >> 2, scol = (lane & 3) * 8;

  f32x4 acc[4][4] = {};

  for (int k0 = 0; k0 < 1024; k0 += 32) {
    __syncthreads();
#pragma unroll
    for (int c = 0; c < 2; ++c) {
      const int rb = (w * 2 + c) * 16;
      const unsigned short* ga = A + (size_t)(m0 + rb + srow) * 1024 + k0 + scol;
      __builtin_amdgcn_global_load_lds(
          (const __attribute__((address_space(1))) void*)ga,
          (__attribute__((address_space(3))) void*)(&As[rb * 32]), 16, 0, 0);
      const unsigned short* gb = B + (size_t)(n0 + rb + srow) * 1024 + k0 + scol;
      __builtin_amdgcn_global_load_lds(
          (const __attribute__((address_space(1))) void*)gb,
          (__attribute__((address_space(3))) void*)(&Bs[rb * 32]), 16, 0, 0);
    }
    __syncthreads();
    bf16x8 af[4], bfr[4];
#pragma unroll
    for (int m = 0; m < 4; m++)
      af[m] = *(const bf16x8*)(&As[(wr * 64 + m * 16 + l15) * 32 + l4 * 8]);
#pragma unroll
    for (int n = 0; n < 4; n++)
      bfr[n] = *(const bf16x8*)(&Bs[(wc * 64 + n * 16 + l15) * 32 + l4 * 8]);
#pragma unroll
    for (int m = 0; m < 4; m++)
#pragma unroll
      for (int n = 0; n < 4; n++)
        acc[m][n] = MFMA16(af[m], bfr[n], acc[m][n]);
  }

#pragma unroll
  for (int m = 0; m < 4; m++)
#pragma unroll
    for (int n = 0; n < 4; n++)
#pragma unroll
      for (int r = 0; r < 4; r++) {
        int row = m0 + wr * 64 + m * 16 + l4 * 4 + r;
        int col = n0 + wc * 64 + n * 16 + l15;
        out[(size_t)row * 1024 + col] = acc[m][n][r];
      }
}

// ---------------- Flash attention (causal) ----------------
// grid (32 bh, 32 qtiles). 4 waves x 16 q-rows; kv tiles of 32.

__global__ __launch_bounds__(256) void attn_kernel(
    const unsigned short* __restrict__ Qb,
    const unsigned short* __restrict__ Kb,
    const unsigned short* __restrict__ Vb,
    unsigned short* __restrict__ Ob) {
  __shared__ unsigned short Kt[32][72];       // pad -> 144B rows (2-way = free)
  __shared__ unsigned short Vt[32][72];
  __shared__ unsigned short Pt[4][16][40];    // per-wave P transpose buffer
  const int bh = blockIdx.x, qt = blockIdx.y;
  const int b = bh >> 4, h = bh & 15;
  const int tid = threadIdx.x, w = tid >> 6, lane = tid & 63;
  const int l15 = lane & 15, l4 = lane >> 4;

  // Q fragments (A-operand): row = lane&15, k = (lane>>4)*8+i (+32 for frag 1)
  const int qrow = qt * 64 + w * 16 + l15;
  const unsigned short* qptr = Qb + (size_t)(b * 2048 + qrow) * 1024 + h * 64 + l4 * 8;
  bf16x8 qa0 = *(const bf16x8*)(qptr);
  bf16x8 qa1 = *(const bf16x8*)(qptr + 32);

  f32x4 oacc[4] = {};
  float mrow[4] = {-1e30f, -1e30f, -1e30f, -1e30f};
  float lrow[4] = {0.f, 0.f, 0.f, 0.f};

  const int strow = tid >> 3, stcol = (tid & 7) * 8;
  const int ntiles = (qt + 1) * 2;
  for (int t = 0; t < ntiles; ++t) {
    const int kv0 = t * 32;
    __syncthreads();
    {
      const size_t gofs = (size_t)(b * 2048 + kv0 + strow) * 1024 + h * 64 + stcol;
      *(int4v*)(&Kt[strow][stcol]) = *(const int4v*)(Kb + gofs);
      *(int4v*)(&Vt[strow][stcol]) = *(const int4v*)(Vb + gofs);
    }
    __syncthreads();

    // QK^T: S[16q][32kv] as two 16-col fragments
    f32x4 sfr[2];
#pragma unroll
    for (int cb = 0; cb < 2; ++cb) {
      bf16x8 kb0 = *(const bf16x8*)(&Kt[cb * 16 + l15][l4 * 8]);
      bf16x8 kb1 = *(const bf16x8*)(&Kt[cb * 16 + l15][32 + l4 * 8]);
      f32x4 z = {0.f, 0.f, 0.f, 0.f};
      z = MFMA16(qa0, kb0, z);
      z = MFMA16(qa1, kb1, z);
      sfr[cb] = z;
    }

    const int qg = qt * 64 + w * 16 + l4 * 4;
#pragma unroll
    for (int r = 0; r < 4; r++) {
      float s0 = sfr[0][r], s1 = sfr[1][r];
      const int q = qg + r;
      if (kv0 + l15 > q)      s0 = -1e30f;
      if (kv0 + 16 + l15 > q) s1 = -1e30f;
      float cur = fmaxf(s0, s1);
      cur = fmaxf(cur, __shfl_xor(cur, 1, 64));
      cur = fmaxf(cur, __shfl_xor(cur, 2, 64));
      cur = fmaxf(cur, __shfl_xor(cur, 4, 64));
      cur = fmaxf(cur, __shfl_xor(cur, 8, 64));
      const float mn = fmaxf(mrow[r], cur);
      const float alpha = __expf(mrow[r] - mn);
      const float p0 = __expf(s0 - mn);
      const float p1 = __expf(s1 - mn);
      float rs = p0 + p1;
      rs += __shfl_xor(rs, 1, 64);
      rs += __shfl_xor(rs, 2, 64);
      rs += __shfl_xor(rs, 4, 64);
      rs += __shfl_xor(rs, 8, 64);
      lrow[r] = lrow[r] * alpha + rs;
      mrow[r] = mn;
#pragma unroll
      for (int d = 0; d < 4; d++) oacc[d][r] *= alpha;
      const int prow = l4 * 4 + r;
      Pt[w][prow][l15]      = f2b(p0);
      Pt[w][prow][16 + l15] = f2b(p1);
    }
    __syncthreads();   // also fences own-wave Pt writes (barrier drains lgkmcnt)

    // PV: A = P[16q][32kv] from LDS, B = V columns
    bf16x8 pa = *(const bf16x8*)(&Pt[w][l15][l4 * 8]);
#pragma unroll
    for (int d = 0; d < 4; d++) {
      U8 vb;
#pragma unroll
      for (int i = 0; i < 8; i++) vb.s[i] = (short)Vt[l4 * 8 + i][d * 16 + l15];
      oacc[d] = MFMA16(pa, vb.v, oacc[d]);
    }
  }

#pragma unroll
  for (int r = 0; r < 4; r++) {
    const float inv = 1.0f / lrow[r];
    const size_t base = (size_t)(b * 2048 + qt * 64 + w * 16 + l4 * 4 + r) * 1024 + h * 64;
#pragma unroll
    for (int d = 0; d < 4; d++)
      Ob[base + d * 16 + l15] = f2b(oacc[d][r] * inv);
  }
}

// ---------------- launch ----------------

extern "C" void kernel_launch(void* const* d_in, const int* in_sizes, int n_in,
                              void* d_out, int out_size, void* d_ws, size_t ws_size,
                              hipStream_t stream) {
  (void)in_sizes; (void)n_in; (void)out_size; (void)ws_size;
  const float* x  = (const float*)d_in[0];
  const int*  tp  = (const int*)d_in[1];
  const float* Wq = (const float*)d_in[2];
  const float* Wk = (const float*)d_in[3];
  const float* Wv = (const float*)d_in[4];
  const float* Wo = (const float*)d_in[5];
  float* out = (float*)d_out;

  char* ws = (char*)d_ws;
  unsigned short* xb    = (unsigned short*)(ws);                       // 8MB
  unsigned short* Ob    = (unsigned short*)(ws);                       // reuses xb after GEMM1
  unsigned short* Wqkvb = (unsigned short*)(ws + (8ull << 20));        // 6MB
  unsigned short* Wob   = (unsigned short*)(ws + (14ull << 20));       // 2MB
  unsigned short* Qb    = (unsigned short*)(ws + (16ull << 20));       // 8MB
  unsigned short* Kb    = (unsigned short*)(ws + (24ull << 20));       // 8MB
  unsigned short* Vb    = (unsigned short*)(ws + (32ull << 20));       // 8MB
  float* cosT = (float*)(ws + (40ull << 20));                          // 256KB
  float* sinT = (float*)(ws + (40ull << 20) + 2048 * 32 * 4);          // 256KB

  // prep: bf16 conversions (1/sqrt(dk)=1/8 folded into Wq) + RoPE tables
  convert_f32_bf16<<<4096, 256, 0, stream>>>(x, xb, 4096 * 1024, 1.0f);
  convert_f32_bf16<<<1024, 256, 0, stream>>>(Wq, Wqkvb, 1024 * 1024, 0.125f);
  convert_f32_bf16<<<1024, 256, 0, stream>>>(Wk, Wqkvb + 1024 * 1024, 1024 * 1024, 1.0f);
  convert_f32_bf16<<<1024, 256, 0, stream>>>(Wv, Wqkvb + 2 * 1024 * 1024, 1024 * 1024, 1.0f);
  convert_f32_bf16<<<1024, 256, 0, stream>>>(Wo, Wob, 1024 * 1024, 1.0f);
  rope_tables<<<256, 256, 0, stream>>>(tp, cosT, sinT);

  gemm_qkv_kernel<<<dim3(24, 32), 256, 0, stream>>>(xb, Wqkvb, Qb, Kb, Vb, cosT, sinT);
  attn_kernel<<<dim3(32, 32), 256, 0, stream>>>(Qb, Kb, Vb, Ob);
  gemm_out_kernel<<<dim3(8, 32), 256, 0, stream>>>(Ob, Wob, out);
}

// Round 2
// 161.575 us; speedup vs baseline: 1.6601x; 1.6601x over previous
//
#include <hip/hip_runtime.h>
#include <hip/hip_bf16.h>

// MHA forward: b=2, s=2048, d=1024, h=16, dk=64. fp32 in/out, bf16 MFMA internally.
// ws layout (40.5 MB):
//   0      : xb [4096][1024] bf16 (8MB)   -- dead after gemm_qkv, reused as VbT[32][64][2048]
//   8 MB   : Wqkvb [3072][1024] bf16 (6MB)  rows 0-1023=Wq/8, 1024-2047=Wk, 2048-3071=Wv
//   14 MB  : Wob [1024][1024] bf16 (2MB)
//   16 MB  : Qb [4096][1024] bf16 (8MB)  (RoPE'd, pre-scaled 1/8 via Wq)
//   24 MB  : Kb [4096][1024] bf16 (8MB)  (RoPE'd)
//   32 MB  : Vb [4096][1024] bf16 (8MB)  -- dead after transpose_v, reused as Ob
//   40 MB  : cosT [2048][32] f32, sinT [2048][32] f32

typedef __attribute__((ext_vector_type(8))) __bf16 bf16x8;
typedef __attribute__((ext_vector_type(4))) float f32x4;
typedef __attribute__((ext_vector_type(4))) int int4v;
typedef __attribute__((ext_vector_type(2))) unsigned int uint2v;

#define MFMA16(a, b, c) __builtin_amdgcn_mfma_f32_16x16x32_bf16(a, b, c, 0, 0, 0)

__device__ inline unsigned short f2b(float f) {
  unsigned u = __builtin_bit_cast(unsigned, f);
  u = (u + 0x7FFF + ((u >> 16) & 1)) >> 16;   // RNE, finite inputs only
  return (unsigned short)u;
}

// ---------------- fused prep: all bf16 conversions + RoPE tables ----------------

__device__ inline void cvt4(const float* __restrict__ s, unsigned short* __restrict__ d,
                            int i, float sc) {
  float4 v = *(const float4*)(s + i);
  unsigned p0 = (unsigned)f2b(v.x * sc) | ((unsigned)f2b(v.y * sc) << 16);
  unsigned p1 = (unsigned)f2b(v.z * sc) | ((unsigned)f2b(v.w * sc) << 16);
  uint2v p = {p0, p1};
  *(uint2v*)(d + i) = p;
}

__global__ __launch_bounds__(256) void prep_kernel(
    const float* __restrict__ x, const float* __restrict__ Wq,
    const float* __restrict__ Wk, const float* __restrict__ Wv,
    const float* __restrict__ Wo, const int* __restrict__ tp,
    unsigned short* __restrict__ xb, unsigned short* __restrict__ Wqkvb,
    unsigned short* __restrict__ Wob, float* __restrict__ cosT,
    float* __restrict__ sinT) {
  int t = blockIdx.x * 256 + threadIdx.x;
  if (t < 1048576) {
    cvt4(x, xb, t * 4, 1.0f);
  } else if (t < 1310720) {
    cvt4(Wq, Wqkvb, (t - 1048576) * 4, 0.125f);
  } else if (t < 1572864) {
    cvt4(Wk, Wqkvb + 1048576, (t - 1310720) * 4, 1.0f);
  } else if (t < 1835008) {
    cvt4(Wv, Wqkvb + 2097152, (t - 1572864) * 4, 1.0f);
  } else if (t < 2097152) {
    cvt4(Wo, Wob, (t - 1835008) * 4, 1.0f);
  } else {
    int base = (t - 2097152) * 4;
#pragma unroll
    for (int j = 0; j < 4; ++j) {
      int idx = base + j;
      int p = idx >> 5, i = idx & 31;
      float pos = (float)tp[p];
      float freq = powf(10000.0f, -(float)i / 32.0f);
      float ang = pos * freq;
      cosT[idx] = cosf(ang);
      sinT[idx] = sinf(ang);
    }
  }
}

// ---------------- GEMM 1: QKV projection + RoPE epilogue ----------------

__global__ __launch_bounds__(256) void gemm_qkv_kernel(
    const unsigned short* __restrict__ A,    // xb
    const unsigned short* __restrict__ B,    // Wqkvb
    unsigned short* __restrict__ Qb, unsigned short* __restrict__ Kb,
    unsigned short* __restrict__ Vb,
    const float* __restrict__ cosT, const float* __restrict__ sinT) {
  __shared__ unsigned short As[128 * 32];
  __shared__ unsigned short Bs[128 * 32];
  const int m0 = blockIdx.y * 128, n0 = blockIdx.x * 128;
  const int tid = threadIdx.x, w = tid >> 6, lane = tid & 63;
  const int l15 = lane & 15, l4 = lane >> 4;
  const int wr = w >> 1, wc = w & 1;
  const int srow = lane >> 2, scol = (lane & 3) * 8;

  f32x4 acc[4][4] = {};

  for (int k0 = 0; k0 < 1024; k0 += 32) {
    __syncthreads();
#pragma unroll
    for (int c = 0; c < 2; ++c) {
      const int rb = (w * 2 + c) * 16;
      const unsigned short* ga = A + (size_t)(m0 + rb + srow) * 1024 + k0 + scol;
      __builtin_amdgcn_global_load_lds(
          (const __attribute__((address_space(1))) void*)ga,
          (__attribute__((address_space(3))) void*)(&As[rb * 32]), 16, 0, 0);
      const unsigned short* gb = B + (size_t)(n0 + rb + srow) * 1024 + k0 + scol;
      __builtin_amdgcn_global_load_lds(
          (const __attribute__((address_space(1))) void*)gb,
          (__attribute__((address_space(3))) void*)(&Bs[rb * 32]), 16, 0, 0);
    }
    __syncthreads();
    bf16x8 af[4], bfr[4];
#pragma unroll
    for (int m = 0; m < 4; m++)
      af[m] = *(const bf16x8*)(&As[(wr * 64 + m * 16 + l15) * 32 + l4 * 8]);
#pragma unroll
    for (int n = 0; n < 4; n++)
      bfr[n] = *(const bf16x8*)(&Bs[(wc * 64 + n * 16 + l15) * 32 + l4 * 8]);
#pragma unroll
    for (int m = 0; m < 4; m++)
#pragma unroll
      for (int n = 0; n < 4; n++)
        acc[m][n] = MFMA16(af[m], bfr[n], acc[m][n]);
  }

  const bool rope = (n0 < 2048);
  unsigned short* dst = (n0 < 1024) ? Qb : (n0 < 2048 ? Kb : Vb);
  const int cbase = (n0 & 1023);
#pragma unroll
  for (int m = 0; m < 4; m++) {
#pragma unroll
    for (int n = 0; n < 4; n++) {
#pragma unroll
      for (int r = 0; r < 4; r++) {
        int row = m0 + wr * 64 + m * 16 + l4 * 4 + r;
        int col = cbase + wc * 64 + n * 16 + l15;
        float v = acc[m][n][r];
        float pv = __shfl_xor(v, 1, 64);      // value of col^1 (lives in lane^1)
        unsigned pk;
        if (rope) {
          float x1 = (l15 & 1) ? pv : v;
          float x2 = (l15 & 1) ? v : pv;
          int pos = row & 2047;
          int pi = (col & 63) >> 1;
          float c = cosT[pos * 32 + pi], s = sinT[pos * 32 + pi];
          float r1 = fmaf(x1, c, -x2 * s);
          float r2 = fmaf(x2, c, x1 * s);
          pk = (unsigned)f2b(r1) | ((unsigned)f2b(r2) << 16);
        } else {
          pk = (unsigned)f2b(v) | ((unsigned)f2b(pv) << 16);
        }
        if (!(l15 & 1))
          *(unsigned*)(dst + (size_t)row * 1024 + col) = pk;
      }
    }
  }
}

// ---------------- GEMM 2: output projection ----------------

__global__ __launch_bounds__(256) void gemm_out_kernel(
    const unsigned short* __restrict__ A,    // Ob [4096][1024]
    const unsigned short* __restrict__ B,    // Wob [1024][1024]
    float* __restrict__ out) {
  __shared__ unsigned short As[128 * 32];
  __shared__ unsigned short Bs[128 * 32];
  const int m0 = blockIdx.y * 128, n0 = blockIdx.x * 128;
  const int tid = threadIdx.x, w = tid >> 6, lane = tid & 63;
  const int l15 = lane & 15, l4 = lane >> 4;
  const int wr = w >> 1, wc = w & 1;
  const int srow = lane >> 2, scol = (lane & 3) * 8;

  f32x4 acc[4][4] = {};

  for (int k0 = 0; k0 < 1024; k0 += 32) {
    __syncthreads();
#pragma unroll
    for (int c = 0; c < 2; ++c) {
      const int rb = (w * 2 + c) * 16;
      const unsigned short* ga = A + (size_t)(m0 + rb + srow) * 1024 + k0 + scol;
      __builtin_amdgcn_global_load_lds(
          (const __attribute__((address_space(1))) void*)ga,
          (__attribute__((address_space(3))) void*)(&As[rb * 32]), 16, 0, 0);
      const unsigned short* gb = B + (size_t)(n0 + rb + srow) * 1024 + k0 + scol;
      __builtin_amdgcn_global_load_lds(
          (const __attribute__((address_space(1))) void*)gb,
          (__attribute__((address_space(3))) void*)(&Bs[rb * 32]), 16, 0, 0);
    }
    __syncthreads();
    bf16x8 af[4], bfr[4];
#pragma unroll
    for (int m = 0; m < 4; m++)
      af[m] = *(const bf16x8*)(&As[(wr * 64 + m * 16 + l15) * 32 + l4 * 8]);
#pragma unroll
    for (int n = 0; n < 4; n++)
      bfr[n] = *(const bf16x8*)(&Bs[(wc * 64 + n * 16 + l15) * 32 + l4 * 8]);
#pragma unroll
    for (int m = 0; m < 4; m++)
#pragma unroll
      for (int n = 0; n < 4; n++)
        acc[m][n] = MFMA16(af[m], bfr[n], acc[m][n]);
  }

#pragma unroll
  for (int m = 0; m < 4; m++)
#pragma unroll
    for (int n = 0; n < 4; n++)
#pragma unroll
      for (int r = 0; r < 4; r++) {
        int row = m0 + wr * 64 + m * 16 + l4 * 4 + r;
        int col = n0 + wc * 64 + n * 16 + l15;
        out[(size_t)row * 1024 + col] = acc[m][n][r];
      }
}

// ---------------- V transpose: Vb[4096][1024] -> VbT[32 bh][64 dk][2048 seq] ----------------
// conflict-free: column-gather uses same-dword broadcast (dk pairs share a word)

__global__ __launch_bounds__(256) void transpose_v(
    const unsigned short* __restrict__ Vb, unsigned short* __restrict__ VbT) {
  __shared__ unsigned short T[128][72];
  const int bh = blockIdx.x, st = blockIdx.y;   // 32 x 16 (128 seq per tile)
  const int b = bh >> 4, h = bh & 15;
  const int tid = threadIdx.x;
  {
    const int r = tid >> 1, c = (tid & 1) * 32;
    const unsigned short* g = Vb + (size_t)(b * 2048 + st * 128 + r) * 1024 + h * 64 + c;
#pragma unroll
    for (int j = 0; j < 4; ++j)
      *(int4v*)(&T[r][c + j * 8]) = *(const int4v*)(g + j * 8);
  }
  __syncthreads();
  {
    const int dk = tid & 63, sc = (tid >> 6) * 32;
    unsigned pk[16];
#pragma unroll
    for (int j = 0; j < 16; ++j)
      pk[j] = (unsigned)T[sc + 2 * j][dk] | ((unsigned)T[sc + 2 * j + 1][dk] << 16);
    unsigned short* g = VbT + (size_t)bh * 131072 + (size_t)dk * 2048 + st * 128 + sc;
#pragma unroll
    for (int j = 0; j < 4; ++j) {
      int4v ov;
      ov[0] = (int)pk[j * 4 + 0]; ov[1] = (int)pk[j * 4 + 1];
      ov[2] = (int)pk[j * 4 + 2]; ov[3] = (int)pk[j * 4 + 3];
      *(int4v*)(g + j * 8) = ov;
    }
  }
}

// ---------------- Flash attention (causal), KVBLK=64, swizzled LDS, dbuf ----------------

__device__ inline void stage_tiles(const unsigned short* __restrict__ Kgb,
                                   const unsigned short* __restrict__ Vgb,
                                   unsigned short* KsBuf, unsigned short* VsBuf,
                                   int kv0, int w, int lane) {
#pragma unroll
  for (int c = 0; c < 2; ++c) {
    const int rowbase = w * 16 + c * 8;
    const int row = rowbase + (lane >> 3);
    const int chunk = (lane & 7) ^ (lane >> 3);    // inverse swizzle on global source
    const unsigned short* gk = Kgb + (size_t)(kv0 + row) * 1024 + chunk * 8;
    __builtin_amdgcn_global_load_lds(
        (const __attribute__((address_space(1))) void*)gk,
        (__attribute__((address_space(3))) void*)(KsBuf + rowbase * 64), 16, 0, 0);
    const unsigned short* gv = Vgb + (size_t)row * 2048 + kv0 + chunk * 8;
    __builtin_amdgcn_global_load_lds(
        (const __attribute__((address_space(1))) void*)gv,
        (__attribute__((address_space(3))) void*)(VsBuf + rowbase * 64), 16, 0, 0);
  }
}

__global__ __launch_bounds__(256) void attn_kernel(
    const unsigned short* __restrict__ Qb,
    const unsigned short* __restrict__ Kb,
    const unsigned short* __restrict__ VbT,   // [32][64][2048]
    unsigned short* __restrict__ Ob) {
  __shared__ unsigned short Ks[2][64 * 64];   // [kv 64][dk 64], chunk-swizzled
  __shared__ unsigned short Vs[2][64 * 64];   // [dk 64][kv 64], chunk-swizzled
  __shared__ unsigned short Pt[4][16][72];    // per-wave P, padded
  const int bh = blockIdx.x;
  const int qt = 31 - blockIdx.y;             // longest blocks dispatch first
  const int b = bh >> 4, h = bh & 15;
  const int tid = threadIdx.x, w = tid >> 6, lane = tid & 63;
  const int l15 = lane & 15, l4 = lane >> 4;

  const int qrow = qt * 64 + w * 16 + l15;
  const unsigned short* qptr = Qb + (size_t)(b * 2048 + qrow) * 1024 + h * 64 + l4 * 8;
  const bf16x8 qa0 = *(const bf16x8*)(qptr);
  const bf16x8 qa1 = *(const bf16x8*)(qptr + 32);

  f32x4 oacc[4] = {};
  float mrow[4] = {-1e30f, -1e30f, -1e30f, -1e30f};
  float lrow[4] = {0.f, 0.f, 0.f, 0.f};

  const unsigned short* Kgb = Kb + (size_t)b * 2048 * 1024 + h * 64;
  const unsigned short* Vgb = VbT + (size_t)bh * 131072;

  stage_tiles(Kgb, Vgb, &Ks[0][0], &Vs[0][0], 0, w, lane);
  asm volatile("s_waitcnt vmcnt(0)" ::: "memory");
  __syncthreads();

  int cur = 0;
  for (int t = 0; t <= qt; ++t) {
    if (t < qt)
      stage_tiles(Kgb, Vgb, &Ks[cur ^ 1][0], &Vs[cur ^ 1][0], (t + 1) * 64, w, lane);

    // QK^T: S[16q][64kv], 4 col-fragments x (K=64 -> 2 MFMAs)
    const unsigned short* ksb = &Ks[cur][0];
    f32x4 sfr[4];
#pragma unroll
    for (int cb = 0; cb < 4; ++cb) {
      const int krow = cb * 16 + l15;
      const int sw = l15 & 7;
      bf16x8 kb0 = *(const bf16x8*)((const char*)ksb + krow * 128 + ((l4 ^ sw) * 16));
      bf16x8 kb1 = *(const bf16x8*)((const char*)ksb + krow * 128 + (((l4 + 4) ^ sw) * 16));
      f32x4 z = {0.f, 0.f, 0.f, 0.f};
      z = MFMA16(qa0, kb0, z);
      z = MFMA16(qa1, kb1, z);
      sfr[cb] = z;
    }

    const bool diag = (t == qt);
#pragma unroll
    for (int r = 0; r < 4; ++r) {
      float s0 = sfr[0][r], s1 = sfr[1][r], s2 = sfr[2][r], s3 = sfr[3][r];
      if (diag) {
        const int qloc = w * 16 + l4 * 4 + r;
        if (l15 > qloc)      s0 = -1e30f;
        if (16 + l15 > qloc) s1 = -1e30f;
        if (32 + l15 > qloc) s2 = -1e30f;
        if (48 + l15 > qloc) s3 = -1e30f;
      }
      float cm = fmaxf(fmaxf(s0, s1), fmaxf(s2, s3));
      cm = fmaxf(cm, __shfl_xor(cm, 1, 64));
      cm = fmaxf(cm, __shfl_xor(cm, 2, 64));
      cm = fmaxf(cm, __shfl_xor(cm, 4, 64));
      cm = fmaxf(cm, __shfl_xor(cm, 8, 64));
      const float mn = fmaxf(mrow[r], cm);
      const float alpha = __expf(mrow[r] - mn);
      const float p0 = __expf(s0 - mn);
      const float p1 = __expf(s1 - mn);
      const float p2 = __expf(s2 - mn);
      const float p3 = __expf(s3 - mn);
      float rs = (p0 + p1) + (p2 + p3);
      rs += __shfl_xor(rs, 1, 64);
      rs += __shfl_xor(rs, 2, 64);
      rs += __shfl_xor(rs, 4, 64);
      rs += __shfl_xor(rs, 8, 64);
      lrow[r] = lrow[r] * alpha + rs;
      mrow[r] = mn;
#pragma unroll
      for (int d = 0; d < 4; ++d) oacc[d][r] *= alpha;
      const int prow = l4 * 4 + r;
      Pt[w][prow][l15]      = f2b(p0);
      Pt[w][prow][16 + l15] = f2b(p1);
      Pt[w][prow][32 + l15] = f2b(p2);
      Pt[w][prow][48 + l15] = f2b(p3);
    }

    // same-wave fence: Pt writes -> Pt reads (Pt is wave-private, no block barrier)
    asm volatile("s_waitcnt lgkmcnt(0)" ::: "memory");
    __builtin_amdgcn_sched_barrier(0);

    // PV: O[16q][64dk] += P[16q][64kv] @ V^T[dk][kv]
    const unsigned short* vsb = &Vs[cur][0];
    bf16x8 pa0 = *(const bf16x8*)(&Pt[w][l15][l4 * 8]);
    bf16x8 pa1 = *(const bf16x8*)(&Pt[w][l15][32 + l4 * 8]);
#pragma unroll
    for (int d = 0; d < 4; ++d) {
      const int vrow = d * 16 + l15;
      const int sw = l15 & 7;
      bf16x8 vb0 = *(const bf16x8*)((const char*)vsb + vrow * 128 + ((l4 ^ sw) * 16));
      bf16x8 vb1 = *(const bf16x8*)((const char*)vsb + vrow * 128 + (((l4 + 4) ^ sw) * 16));
      oacc[d] = MFMA16(pa0, vb0, oacc[d]);
      oacc[d] = MFMA16(pa1, vb1, oacc[d]);
    }

    if (t < qt) {
      asm volatile("s_waitcnt vmcnt(0)" ::: "memory");
      __syncthreads();
      cur ^= 1;
    }
  }

#pragma unroll
  for (int r = 0; r < 4; ++r) {
    const float inv = 1.0f / lrow[r];
    const size_t base = (size_t)(b * 2048 + qt * 64 + w * 16 + l4 * 4 + r) * 1024 + h * 64;
#pragma unroll
    for (int d = 0; d < 4; ++d) {
      float ov = oacc[d][r] * inv;
      float pov = __shfl_xor(ov, 1, 64);
      if (!(l15 & 1))
        *(unsigned*)(Ob + base + d * 16 + l15) =
            (unsigned)f2b(ov) | ((unsigned)f2b(pov) << 16);
    }
  }
}

// ---------------- launch ----------------

extern "C" void kernel_launch(void* const* d_in, const int* in_sizes, int n_in,
                              void* d_out, int out_size, void* d_ws, size_t ws_size,
                              hipStream_t stream) {
  (void)in_sizes; (void)n_in; (void)out_size; (void)ws_size;
  const float* x  = (const float*)d_in[0];
  const int*  tp  = (const int*)d_in[1];
  const float* Wq = (const float*)d_in[2];
  const float* Wk = (const float*)d_in[3];
  const float* Wv = (const float*)d_in[4];
  const float* Wo = (const float*)d_in[5];
  float* out = (float*)d_out;

  char* ws = (char*)d_ws;
  unsigned short* xb    = (unsigned short*)(ws);                       // 8MB
  unsigned short* VbT   = (unsigned short*)(ws);                       // reuses xb
  unsigned short* Wqkvb = (unsigned short*)(ws + (8ull << 20));        // 6MB
  unsigned short* Wob   = (unsigned short*)(ws + (14ull << 20));       // 2MB
  unsigned short* Qb    = (unsigned short*)(ws + (16ull << 20));       // 8MB
  unsigned short* Kb    = (unsigned short*)(ws + (24ull << 20));       // 8MB
  unsigned short* Vb    = (unsigned short*)(ws + (32ull << 20));       // 8MB
  unsigned short* Ob    = (unsigned short*)(ws + (32ull << 20));       // reuses Vb
  float* cosT = (float*)(ws + (40ull << 20));
  float* sinT = (float*)(ws + (40ull << 20) + 2048 * 32 * 4);

  prep_kernel<<<8256, 256, 0, stream>>>(x, Wq, Wk, Wv, Wo, tp, xb, Wqkvb, Wob, cosT, sinT);
  gemm_qkv_kernel<<<dim3(24, 32), 256, 0, stream>>>(xb, Wqkvb, Qb, Kb, Vb, cosT, sinT);
  transpose_v<<<dim3(32, 16), 256, 0, stream>>>(Vb, VbT);
  attn_kernel<<<dim3(32, 32), 256, 0, stream>>>(Qb, Kb, VbT, Ob);
  gemm_out_kernel<<<dim3(8, 32), 256, 0, stream>>>(Ob, Wob, out);
}

// Round 3
// 143.699 us; speedup vs baseline: 1.8666x; 1.1244x over previous
//
#include <hip/hip_runtime.h>
#include <hip/hip_bf16.h>

// MHA forward: b=2, s=2048, d=1024, h=16, dk=64. fp32 in/out, bf16 MFMA internally.
// ws layout (40.5 MB):
//   0      : xb [4096][1024] bf16 (8MB)   -- dead after gemm_qkv, reused as VbT[32][64][2048]
//   8 MB   : Wqkvb [3072][1024] bf16 (6MB)  rows 0-1023=Wq*log2e/8, 1024-2047=Wk, 2048-3071=Wv
//   14 MB  : Wob [1024][1024] bf16 (2MB)
//   16 MB  : Qb [4096][1024] bf16 (8MB)  (RoPE'd, pre-scaled log2e/8 via Wq -> scores in log2 domain)
//   24 MB  : Kb [4096][1024] bf16 (8MB)  (RoPE'd)
//   32 MB  : Vb [4096][1024] bf16 (8MB)  -- dead after transpose_v, reused as Ob
//   40 MB  : cosT [2048][32] f32, sinT [2048][32] f32

typedef __attribute__((ext_vector_type(8))) __bf16 bf16x8;
typedef __attribute__((ext_vector_type(4))) float f32x4;
typedef __attribute__((ext_vector_type(16))) float f32x16;
typedef __attribute__((ext_vector_type(4))) int int4v;
typedef __attribute__((ext_vector_type(2))) unsigned int uint2v;

#define MFMA16(a, b, c) __builtin_amdgcn_mfma_f32_16x16x32_bf16(a, b, c, 0, 0, 0)
#define MFMA32(a, b, c) __builtin_amdgcn_mfma_f32_32x32x16_bf16(a, b, c, 0, 0, 0)

__device__ inline unsigned short f2b(float f) {
  unsigned u = __builtin_bit_cast(unsigned, f);
  u = (u + 0x7FFF + ((u >> 16) & 1)) >> 16;   // RNE, finite inputs only
  return (unsigned short)u;
}

__device__ inline unsigned cvtpk(float lo, float hi) {
  unsigned r;
  asm("v_cvt_pk_bf16_f32 %0, %1, %2" : "=v"(r) : "v"(lo), "v"(hi));
  return r;
}

// permlane32_swap: o0 = {lane<32: a; lane>=32: b[partner]}, o1 = {lane<32: a[partner]; lane>=32: b}
__device__ inline void plswap(unsigned a, unsigned b, unsigned& o0, unsigned& o1) {
#if __has_builtin(__builtin_amdgcn_permlane32_swap)
  auto r = __builtin_amdgcn_permlane32_swap(a, b, false, false);
  o0 = r[0];
  o1 = r[1];
#else
  unsigned sa = (unsigned)__shfl_xor((int)a, 32, 64);
  unsigned sb = (unsigned)__shfl_xor((int)b, 32, 64);
  bool hi = (threadIdx.x & 32) != 0;
  o0 = hi ? sb : a;
  o1 = hi ? b : sa;
#endif
}

__device__ inline float fexp2(float x) {
#if __has_builtin(__builtin_amdgcn_exp2f)
  return __builtin_amdgcn_exp2f(x);
#else
  return exp2f(x);
#endif
}

// ---------------- fused prep: all bf16 conversions + RoPE tables ----------------

__device__ inline void cvt4(const float* __restrict__ s, unsigned short* __restrict__ d,
                            int i, float sc) {
  float4 v = *(const float4*)(s + i);
  unsigned p0 = (unsigned)f2b(v.x * sc) | ((unsigned)f2b(v.y * sc) << 16);
  unsigned p1 = (unsigned)f2b(v.z * sc) | ((unsigned)f2b(v.w * sc) << 16);
  uint2v p = {p0, p1};
  *(uint2v*)(d + i) = p;
}

__global__ __launch_bounds__(256) void prep_kernel(
    const float* __restrict__ x, const float* __restrict__ Wq,
    const float* __restrict__ Wk, const float* __restrict__ Wv,
    const float* __restrict__ Wo, const int* __restrict__ tp,
    unsigned short* __restrict__ xb, unsigned short* __restrict__ Wqkvb,
    unsigned short* __restrict__ Wob, float* __restrict__ cosT,
    float* __restrict__ sinT) {
  int t = blockIdx.x * 256 + threadIdx.x;
  if (t < 1048576) {
    cvt4(x, xb, t * 4, 1.0f);
  } else if (t < 1310720) {
    cvt4(Wq, Wqkvb, (t - 1048576) * 4, 0.18033688f);   // (1/8)*log2(e)
  } else if (t < 1572864) {
    cvt4(Wk, Wqkvb + 1048576, (t - 1310720) * 4, 1.0f);
  } else if (t < 1835008) {
    cvt4(Wv, Wqkvb + 2097152, (t - 1572864) * 4, 1.0f);
  } else if (t < 2097152) {
    cvt4(Wo, Wob, (t - 1835008) * 4, 1.0f);
  } else {
    int base = (t - 2097152) * 4;
#pragma unroll
    for (int j = 0; j < 4; ++j) {
      int idx = base + j;
      int p = idx >> 5, i = idx & 31;
      float pos = (float)tp[p];
      float freq = powf(10000.0f, -(float)i / 32.0f);
      float ang = pos * freq;
      cosT[idx] = cosf(ang);
      sinT[idx] = sinf(ang);
    }
  }
}

// ---------------- GEMM 1: QKV projection + RoPE epilogue ----------------

__global__ __launch_bounds__(256) void gemm_qkv_kernel(
    const unsigned short* __restrict__ A,    // xb
    const unsigned short* __restrict__ B,    // Wqkvb
    unsigned short* __restrict__ Qb, unsigned short* __restrict__ Kb,
    unsigned short* __restrict__ Vb,
    const float* __restrict__ cosT, const float* __restrict__ sinT) {
  __shared__ unsigned short As[128 * 32];
  __shared__ unsigned short Bs[128 * 32];
  const int m0 = blockIdx.y * 128, n0 = blockIdx.x * 128;
  const int tid = threadIdx.x, w = tid >> 6, lane = tid & 63;
  const int l15 = lane & 15, l4 = lane >> 4;
  const int wr = w >> 1, wc = w & 1;
  const int srow = lane >> 2, scol = (lane & 3) * 8;

  f32x4 acc[4][4] = {};

  for (int k0 = 0; k0 < 1024; k0 += 32) {
    __syncthreads();
#pragma unroll
    for (int c = 0; c < 2; ++c) {
      const int rb = (w * 2 + c) * 16;
      const unsigned short* ga = A + (size_t)(m0 + rb + srow) * 1024 + k0 + scol;
      __builtin_amdgcn_global_load_lds(
          (const __attribute__((address_space(1))) void*)ga,
          (__attribute__((address_space(3))) void*)(&As[rb * 32]), 16, 0, 0);
      const unsigned short* gb = B + (size_t)(n0 + rb + srow) * 1024 + k0 + scol;
      __builtin_amdgcn_global_load_lds(
          (const __attribute__((address_space(1))) void*)gb,
          (__attribute__((address_space(3))) void*)(&Bs[rb * 32]), 16, 0, 0);
    }
    __syncthreads();
    bf16x8 af[4], bfr[4];
#pragma unroll
    for (int m = 0; m < 4; m++)
      af[m] = *(const bf16x8*)(&As[(wr * 64 + m * 16 + l15) * 32 + l4 * 8]);
#pragma unroll
    for (int n = 0; n < 4; n++)
      bfr[n] = *(const bf16x8*)(&Bs[(wc * 64 + n * 16 + l15) * 32 + l4 * 8]);
#pragma unroll
    for (int m = 0; m < 4; m++)
#pragma unroll
      for (int n = 0; n < 4; n++)
        acc[m][n] = MFMA16(af[m], bfr[n], acc[m][n]);
  }

  const bool rope = (n0 < 2048);
  unsigned short* dst = (n0 < 1024) ? Qb : (n0 < 2048 ? Kb : Vb);
  const int cbase = (n0 & 1023);
#pragma unroll
  for (int m = 0; m < 4; m++) {
#pragma unroll
    for (int n = 0; n < 4; n++) {
#pragma unroll
      for (int r = 0; r < 4; r++) {
        int row = m0 + wr * 64 + m * 16 + l4 * 4 + r;
        int col = cbase + wc * 64 + n * 16 + l15;
        float v = acc[m][n][r];
        float pv = __shfl_xor(v, 1, 64);      // value of col^1 (lives in lane^1)
        unsigned pk;
        if (rope) {
          float x1 = (l15 & 1) ? pv : v;
          float x2 = (l15 & 1) ? v : pv;
          int pos = row & 2047;
          int pi = (col & 63) >> 1;
          float c = cosT[pos * 32 + pi], s = sinT[pos * 32 + pi];
          float r1 = fmaf(x1, c, -x2 * s);
          float r2 = fmaf(x2, c, x1 * s);
          pk = (unsigned)f2b(r1) | ((unsigned)f2b(r2) << 16);
        } else {
          pk = (unsigned)f2b(v) | ((unsigned)f2b(pv) << 16);
        }
        if (!(l15 & 1))
          *(unsigned*)(dst + (size_t)row * 1024 + col) = pk;
      }
    }
  }
}

// ---------------- GEMM 2: output projection ----------------

__global__ __launch_bounds__(256) void gemm_out_kernel(
    const unsigned short* __restrict__ A,    // Ob [4096][1024]
    const unsigned short* __restrict__ B,    // Wob [1024][1024]
    float* __restrict__ out) {
  __shared__ unsigned short As[128 * 32];
  __shared__ unsigned short Bs[128 * 32];
  const int m0 = blockIdx.y * 128, n0 = blockIdx.x * 128;
  const int tid = threadIdx.x, w = tid >> 6, lane = tid & 63;
  const int l15 = lane & 15, l4 = lane >> 4;
  const int wr = w >> 1, wc = w & 1;
  const int srow = lane >> 2, scol = (lane & 3) * 8;

  f32x4 acc[4][4] = {};

  for (int k0 = 0; k0 < 1024; k0 += 32) {
    __syncthreads();
#pragma unroll
    for (int c = 0; c < 2; ++c) {
      const int rb = (w * 2 + c) * 16;
      const unsigned short* ga = A + (size_t)(m0 + rb + srow) * 1024 + k0 + scol;
      __builtin_amdgcn_global_load_lds(
          (const __attribute__((address_space(1))) void*)ga,
          (__attribute__((address_space(3))) void*)(&As[rb * 32]), 16, 0, 0);
      const unsigned short* gb = B + (size_t)(n0 + rb + srow) * 1024 + k0 + scol;
      __builtin_amdgcn_global_load_lds(
          (const __attribute__((address_space(1))) void*)gb,
          (__attribute__((address_space(3))) void*)(&Bs[rb * 32]), 16, 0, 0);
    }
    __syncthreads();
    bf16x8 af[4], bfr[4];
#pragma unroll
    for (int m = 0; m < 4; m++)
      af[m] = *(const bf16x8*)(&As[(wr * 64 + m * 16 + l15) * 32 + l4 * 8]);
#pragma unroll
    for (int n = 0; n < 4; n++)
      bfr[n] = *(const bf16x8*)(&Bs[(wc * 64 + n * 16 + l15) * 32 + l4 * 8]);
#pragma unroll
    for (int m = 0; m < 4; m++)
#pragma unroll
      for (int n = 0; n < 4; n++)
        acc[m][n] = MFMA16(af[m], bfr[n], acc[m][n]);
  }

#pragma unroll
  for (int m = 0; m < 4; m++)
#pragma unroll
    for (int n = 0; n < 4; n++)
#pragma unroll
      for (int r = 0; r < 4; r++) {
        int row = m0 + wr * 64 + m * 16 + l4 * 4 + r;
        int col = n0 + wc * 64 + n * 16 + l15;
        out[(size_t)row * 1024 + col] = acc[m][n][r];
      }
}

// ---------------- V transpose: Vb[4096][1024] -> VbT[32 bh][64 dk][2048 seq] ----------------

__global__ __launch_bounds__(256) void transpose_v(
    const unsigned short* __restrict__ Vb, unsigned short* __restrict__ VbT) {
  __shared__ unsigned short T[128][72];
  const int bh = blockIdx.x, st = blockIdx.y;   // 32 x 16 (128 seq per tile)
  const int b = bh >> 4, h = bh & 15;
  const int tid = threadIdx.x;
  {
    const int r = tid >> 1, c = (tid & 1) * 32;
    const unsigned short* g = Vb + (size_t)(b * 2048 + st * 128 + r) * 1024 + h * 64 + c;
#pragma unroll
    for (int j = 0; j < 4; ++j)
      *(int4v*)(&T[r][c + j * 8]) = *(const int4v*)(g + j * 8);
  }
  __syncthreads();
  {
    const int dk = tid & 63, sc = (tid >> 6) * 32;
    unsigned pk[16];
#pragma unroll
    for (int j = 0; j < 16; ++j)
      pk[j] = (unsigned)T[sc + 2 * j][dk] | ((unsigned)T[sc + 2 * j + 1][dk] << 16);
    unsigned short* g = VbT + (size_t)bh * 131072 + (size_t)dk * 2048 + st * 128 + sc;
#pragma unroll
    for (int j = 0; j < 4; ++j) {
      int4v ov;
      ov[0] = (int)pk[j * 4 + 0]; ov[1] = (int)pk[j * 4 + 1];
      ov[2] = (int)pk[j * 4 + 2]; ov[3] = (int)pk[j * 4 + 3];
      *(int4v*)(g + j * 8) = ov;
    }
  }
}

// ---------------- Flash attention (causal), 32x32 MFMA, swapped operands ----------------
// Per wave: 32 q-rows; block: 4 waves = 128 q. KVBLK=64. P stays in registers
// (cvt_pk + permlane32_swap), softmax reductions in-register + 1 shfl.

__device__ inline void stage_tiles(const unsigned short* __restrict__ Kgb,
                                   const unsigned short* __restrict__ Vgb,
                                   unsigned short* KsBuf, unsigned short* VsBuf,
                                   int kv0, int w, int lane) {
#pragma unroll
  for (int c = 0; c < 2; ++c) {
    const int rowbase = w * 16 + c * 8;
    const int row = rowbase + (lane >> 3);
    const int chunk = (lane & 7) ^ (lane >> 3);    // inverse swizzle on global source
    const unsigned short* gk = Kgb + (size_t)(kv0 + row) * 1024 + chunk * 8;
    __builtin_amdgcn_global_load_lds(
        (const __attribute__((address_space(1))) void*)gk,
        (__attribute__((address_space(3))) void*)(KsBuf + rowbase * 64), 16, 0, 0);
    const unsigned short* gv = Vgb + (size_t)row * 2048 + kv0 + chunk * 8;
    __builtin_amdgcn_global_load_lds(
        (const __attribute__((address_space(1))) void*)gv,
        (__attribute__((address_space(3))) void*)(VsBuf + rowbase * 64), 16, 0, 0);
  }
}

__global__ __launch_bounds__(256) void attn_kernel(
    const unsigned short* __restrict__ Qb,
    const unsigned short* __restrict__ Kb,
    const unsigned short* __restrict__ VbT,   // [32][64][2048]
    unsigned short* __restrict__ Ob) {
  __shared__ unsigned short Ks[2][64 * 64];   // [kv 64][dk 64], chunk-swizzled
  __shared__ unsigned short Vs[2][64 * 64];   // [dk 64][kv 64], chunk-swizzled
  const int bh = blockIdx.x;
  const int y = blockIdx.y;
  const int qt = (y < 8) ? y : (23 - y);      // co-resident pairs sum to constant work
  const int b = bh >> 4, h = bh & 15;
  const int tid = threadIdx.x, w = tid >> 6, lane = tid & 63;
  const int l31 = lane & 31, l32 = lane >> 5;
  const int sw = l31 & 7;

  // Q as B-operand frags: n(q)=l31, k = kk*16 + l32*8 + j
  const unsigned short* qptr =
      Qb + (size_t)(b * 2048 + qt * 128 + w * 32 + l31) * 1024 + h * 64 + l32 * 8;
  bf16x8 qa[4];
#pragma unroll
  for (int kk = 0; kk < 4; ++kk) qa[kk] = *(const bf16x8*)(qptr + kk * 16);

  f32x16 oacc[2] = {};
  float m = -3e38f, l = 0.f;

  const unsigned short* Kgb = Kb + (size_t)b * 2048 * 1024 + h * 64;
  const unsigned short* Vgb = VbT + (size_t)bh * 131072;

  stage_tiles(Kgb, Vgb, &Ks[0][0], &Vs[0][0], 0, w, lane);
  asm volatile("s_waitcnt vmcnt(0)" ::: "memory");
  __syncthreads();

  const int ntiles = 2 * qt + 2;
  int cur = 0;
  for (int t = 0; t < ntiles; ++t) {
    if (t < ntiles - 1)
      stage_tiles(Kgb, Vgb, &Ks[cur ^ 1][0], &Vs[cur ^ 1][0], (t + 1) * 64, w, lane);

    // QK^T swapped: St[f] = mfma32(K_frag, Q_frag) -> S^T[kv][q], q = l31
    const char* ksb = (const char*)(&Ks[cur][0]);
    f32x16 st[2];
#pragma unroll
    for (int f = 0; f < 2; ++f) {
      const char* kb = ksb + (f * 32 + l31) * 128;
      f32x16 z = {};
#pragma unroll
      for (int kk = 0; kk < 4; ++kk) {
        bf16x8 kf = *(const bf16x8*)(kb + ((((kk << 1) | l32) ^ sw) * 16));
        z = MFMA32(kf, qa[kk], z);
      }
      st[f] = z;
    }

    // causal mask (only the last two tiles of this wave can straddle the diagonal)
    if (t >= 2 * qt + (w >> 1)) {
      const int qg = qt * 128 + w * 32 + l31;
      const int kvb = t * 64 + 4 * l32;
#pragma unroll
      for (int f = 0; f < 2; ++f)
#pragma unroll
        for (int reg = 0; reg < 16; ++reg) {
          int kv = kvb + 32 * f + (reg & 3) + 8 * (reg >> 2);
          if (kv > qg) st[f][reg] = -3e38f;
        }
    }

    // row max: in-register tree over 32 + 1 shfl across the lane pair
    float a8[8];
#pragma unroll
    for (int j = 0; j < 8; ++j)
      a8[j] = fmaxf(fmaxf(st[0][j], st[0][j + 8]), fmaxf(st[1][j], st[1][j + 8]));
    float pm = fmaxf(fmaxf(fmaxf(a8[0], a8[1]), fmaxf(a8[2], a8[3])),
                     fmaxf(fmaxf(a8[4], a8[5]), fmaxf(a8[6], a8[7])));
    pm = fmaxf(pm, __shfl_xor(pm, 32, 64));

    // defer-max (exact): only rescale when the running max grew by > 8 (log2 domain)
    if (!__all(pm - m <= 8.0f)) {
      float mn = fmaxf(m, pm);
      float al = fexp2(m - mn);
      l *= al;
#pragma unroll
      for (int df = 0; df < 2; ++df)
#pragma unroll
        for (int reg = 0; reg < 16; ++reg) oacc[df][reg] *= al;
      m = mn;
    }

    // p = exp2(s - m), pack to bf16 pairs
    unsigned pku[2][4][2];
    float rs0 = 0.f, rs1 = 0.f;
#pragma unroll
    for (int f = 0; f < 2; ++f)
#pragma unroll
      for (int rr = 0; rr < 4; ++rr)
#pragma unroll
        for (int i = 0; i < 2; ++i) {
          float p0 = fexp2(st[f][4 * rr + 2 * i] - m);
          float p1 = fexp2(st[f][4 * rr + 2 * i + 1] - m);
          rs0 += p0; rs1 += p1;
          pku[f][rr][i] = cvtpk(p0, p1);
        }
    float rs = rs0 + rs1;
    rs += __shfl_xor(rs, 32, 64);
    l += rs;

    // redistribute P^T into B-operand frags via permlane32_swap
    union FB { unsigned u[4]; bf16x8 v; };
    FB pfrag[4];
#pragma unroll
    for (int kk = 0; kk < 4; ++kk) {
      const int f = kk >> 1, kl = kk & 1;
      unsigned o00, o10, o01, o11;
      plswap(pku[f][2 * kl][0], pku[f][2 * kl + 1][0], o00, o10);
      plswap(pku[f][2 * kl][1], pku[f][2 * kl + 1][1], o01, o11);
      pfrag[kk].u[0] = o00; pfrag[kk].u[1] = o01;
      pfrag[kk].u[2] = o10; pfrag[kk].u[3] = o11;
    }

    // PV swapped: O^T[d][q] += mfma32(V^T_frag, P^T_frag)
    const char* vsb = (const char*)(&Vs[cur][0]);
#pragma unroll
    for (int df = 0; df < 2; ++df) {
      const char* vb = vsb + (df * 32 + l31) * 128;
#pragma unroll
      for (int kk = 0; kk < 4; ++kk) {
        bf16x8 vf = *(const bf16x8*)(vb + ((((kk << 1) | l32) ^ sw) * 16));
        oacc[df] = MFMA32(vf, pfrag[kk].v, oacc[df]);
      }
    }

    if (t < ntiles - 1) {
      asm volatile("s_waitcnt vmcnt(0)" ::: "memory");
      __syncthreads();
      cur ^= 1;
    }
  }

  // epilogue: O[q][d], d = df*32 + 8*rr + 4*l32 + 2i (+1)
  const float inv = 1.0f / l;
  unsigned short* ob =
      Ob + (size_t)(b * 2048 + qt * 128 + w * 32 + l31) * 1024 + h * 64 + 4 * l32;
#pragma unroll
  for (int df = 0; df < 2; ++df)
#pragma unroll
    for (int rr = 0; rr < 4; ++rr)
#pragma unroll
      for (int i = 0; i < 2; ++i) {
        unsigned pk2 = (unsigned)f2b(oacc[df][4 * rr + 2 * i] * inv) |
                       ((unsigned)f2b(oacc[df][4 * rr + 2 * i + 1] * inv) << 16);
        *(unsigned*)(ob + df * 32 + rr * 8 + 2 * i) = pk2;
      }
}

// ---------------- launch ----------------

extern "C" void kernel_launch(void* const* d_in, const int* in_sizes, int n_in,
                              void* d_out, int out_size, void* d_ws, size_t ws_size,
                              hipStream_t stream) {
  (void)in_sizes; (void)n_in; (void)out_size; (void)ws_size;
  const float* x  = (const float*)d_in[0];
  const int*  tp  = (const int*)d_in[1];
  const float* Wq = (const float*)d_in[2];
  const float* Wk = (const float*)d_in[3];
  const float* Wv = (const float*)d_in[4];
  const float* Wo = (const float*)d_in[5];
  float* out = (float*)d_out;

  char* ws = (char*)d_ws;
  unsigned short* xb    = (unsigned short*)(ws);                       // 8MB
  unsigned short* VbT   = (unsigned short*)(ws);                       // reuses xb
  unsigned short* Wqkvb = (unsigned short*)(ws + (8ull << 20));        // 6MB
  unsigned short* Wob   = (unsigned short*)(ws + (14ull << 20));       // 2MB
  unsigned short* Qb    = (unsigned short*)(ws + (16ull << 20));       // 8MB
  unsigned short* Kb    = (unsigned short*)(ws + (24ull << 20));       // 8MB
  unsigned short* Vb    = (unsigned short*)(ws + (32ull << 20));       // 8MB
  unsigned short* Ob    = (unsigned short*)(ws + (32ull << 20));       // reuses Vb
  float* cosT = (float*)(ws + (40ull << 20));
  float* sinT = (float*)(ws + (40ull << 20) + 2048 * 32 * 4);

  prep_kernel<<<8256, 256, 0, stream>>>(x, Wq, Wk, Wv, Wo, tp, xb, Wqkvb, Wob, cosT, sinT);
  gemm_qkv_kernel<<<dim3(24, 32), 256, 0, stream>>>(xb, Wqkvb, Qb, Kb, Vb, cosT, sinT);
  transpose_v<<<dim3(32, 16), 256, 0, stream>>>(Vb, VbT);
  attn_kernel<<<dim3(32, 16), 256, 0, stream>>>(Qb, Kb, VbT, Ob);
  gemm_out_kernel<<<dim3(8, 32), 256, 0, stream>>>(Ob, Wob, out);
}